// Round 21
// baseline (115.723 us; speedup 1.0000x reference)
//
#include <hip/hip_runtime.h>

#define DIMM 1024
#define NHEADS 16
#define HDIM 64
#define WIN 1024
#define GATEIN 20
#define BB 2
#define TT 2048
#define MTOT (BB*TT)   // 4096

typedef __attribute__((ext_vector_type(8))) short short8;
typedef __attribute__((ext_vector_type(4))) float f32x4;
typedef __attribute__((ext_vector_type(16))) float f32x16;
typedef const __attribute__((address_space(1))) void gvoid_t;
typedef __attribute__((address_space(3))) void lvoid_t;

__device__ __forceinline__ unsigned short f2b(float f) {
  union { float f; unsigned u; } c; c.f = f;
  unsigned u = c.u + 0x7fffu + ((c.u >> 16) & 1u);
  return (unsigned short)(u >> 16);
}
__device__ __forceinline__ float b2f(unsigned short s) {
  union { unsigned u; float f; } c; c.u = ((unsigned)s) << 16;
  return c.f;
}
__device__ __forceinline__ unsigned cvt_pk_bf16(float lo, float hi) {
  unsigned r;
  asm("v_cvt_pk_bf16_f32 %0, %1, %2" : "=v"(r) : "v"(lo), "v"(hi));
  return r;
}
__device__ __forceinline__ float max3f(float a, float b, float c) {
  return fmaxf(fmaxf(a, b), c);   // clang fuses to v_max3_f32
}
// cross-half (lane ^ 32) reductions via permlane32_swap (VALU, no DS)
__device__ __forceinline__ float xmax32(float x) {
  union { float f; unsigned u; } c; c.f = x;
  auto pr = __builtin_amdgcn_permlane32_swap(c.u, c.u, false, false);
  union { unsigned u; float f; } a, b; a.u = pr[0]; b.u = pr[1];
  return fmaxf(a.f, b.f);
}
__device__ __forceinline__ float xsum32(float x) {
  union { float f; unsigned u; } c; c.f = x;
  auto pr = __builtin_amdgcn_permlane32_swap(c.u, c.u, false, false);
  union { unsigned u; float f; } a, b; a.u = pr[0]; b.u = pr[1];
  return a.f + b.f;
}

#define QSCALE (0.125f * 1.4426950408889634f)

// ---------------- fused prep: bf16-cast x, Wq|Wk|Wv, Wo; concat biases ----------------
__global__ void prep_kernel(const float* __restrict__ x,  const float* __restrict__ Wq,
                            const float* __restrict__ Wk, const float* __restrict__ Wv,
                            const float* __restrict__ Wo, const float* __restrict__ bq,
                            const float* __restrict__ bk, const float* __restrict__ bv,
                            unsigned short* __restrict__ xb, unsigned short* __restrict__ wqkv,
                            unsigned short* __restrict__ wob, float* __restrict__ bcat) {
  int i = blockIdx.x * blockDim.x + threadIdx.x;
  const float* src; unsigned short* dst; int off;
  if (i < 1048576)      { src = x;  dst = xb;             off = i; }
  else if (i < 1310720) { src = Wq; dst = wqkv;           off = i - 1048576; }
  else if (i < 1572864) { src = Wk; dst = wqkv + 1048576; off = i - 1310720; }
  else if (i < 1835008) { src = Wv; dst = wqkv + 2097152; off = i - 1572864; }
  else if (i < 2097152) { src = Wo; dst = wob;            off = i - 1835008; }
  else {
    int j = i - 2097152;            // 0..767 : bias f32 copy
    if (j < 768) {
      const float* bsrc = (j < 256) ? bq : (j < 512) ? bk : bv;
      int bo = (j & 255) * 4;
      int db = (j < 256) ? 0 : (j < 512) ? 1024 : 2048;
      *(float4*)(bcat + db + bo) = *(const float4*)(bsrc + bo);
    }
    return;
  }
  float4 v = ((const float4*)src)[off];
  union { unsigned short s[4]; uint2 u; } o;
  o.s[0] = f2b(v.x); o.s[1] = f2b(v.y); o.s[2] = f2b(v.z); o.s[3] = f2b(v.w);
  *(uint2*)(dst + (size_t)off * 4) = o.u;
}

// ---------------- gate = sigmoid(x[:, :20] @ Wg^T + bg), [M][H] f32 ----------------
__global__ void gate_kernel(const float* __restrict__ x, const float* __restrict__ Wg,
                            const float* __restrict__ bg, float* __restrict__ gate) {
  int i = blockIdx.x * blockDim.x + threadIdx.x;   // M*H
  if (i >= MTOT * NHEADS) return;
  int h = i & 15;
  int m = i >> 4;
  const float* xr = x + (size_t)m * DIMM;
  const float* wr = Wg + h * GATEIN;
  float z = bg[h];
#pragma unroll
  for (int g = 0; g < GATEIN; ++g) z += xr[g] * wr[g];
  gate[i] = 1.f / (1.f + __expf(-z));
}

// ---------------- QKV GEMM with fused RoPE + relayout epilogue (R14 config) ----------------
// 128x128 tile, 4 waves, swizzled LDS, dbuf 2-phase. N=3072 = [q|k|v].
__global__ __launch_bounds__(256) void gemm_qkv(const unsigned short* __restrict__ A,
                                                const unsigned short* __restrict__ Bw,
                                                const float* __restrict__ bias,
                                                const float* __restrict__ cosb,
                                                const float* __restrict__ sinb,
                                                unsigned short* __restrict__ qr,
                                                unsigned short* __restrict__ kr,
                                                unsigned short* __restrict__ vt) {
  const int K = DIMM;
  __shared__ __align__(16) unsigned short As[2][128 * 32];
  __shared__ __align__(16) unsigned short Bs[2][128 * 32];
  const int tid = threadIdx.x;
  const int lane = tid & 63, wid = tid >> 6;
  const int g = lane >> 4, r16 = lane & 15;
  const int m0 = blockIdx.y * 128, n0 = blockIdx.x * 128;
  const int wr = (wid >> 1) * 64, wc = (wid & 1) * 64;
  const int wbase = wid * 64;

  int oaf[4], obf[4];
#pragma unroll
  for (int mf = 0; mf < 4; ++mf) {
    int row = wr + mf * 16 + r16;
    oaf[mf] = row * 32 + ((g ^ ((row >> 1) & 3)) * 8);
  }
#pragma unroll
  for (int nf = 0; nf < 4; ++nf) {
    int row = wc + nf * 16 + r16;
    obf[nf] = row * 32 + ((g ^ ((row >> 1) & 3)) * 8);
  }

  f32x4 acc[4][4];
#pragma unroll
  for (int i = 0; i < 4; ++i)
#pragma unroll
    for (int j2 = 0; j2 < 4; ++j2) acc[i][j2] = (f32x4){0.f, 0.f, 0.f, 0.f};

  auto stage = [&](int buf, int k0) {
#pragma unroll
    for (int jj = 0; jj < 2; ++jj) {
      int sbase = jj * 256 + wbase;
      int s = sbase + lane;
      int l = s ^ ((s >> 3) & 3);
      const unsigned short* gA = A + (size_t)(m0 + (l >> 2)) * K + k0 + (l & 3) * 8;
      __builtin_amdgcn_global_load_lds((gvoid_t*)gA,
          (lvoid_t*)((char*)&As[buf][0] + sbase * 16), 16, 0, 0);
      const unsigned short* gB = Bw + (size_t)(n0 + (l >> 2)) * K + k0 + (l & 3) * 8;
      __builtin_amdgcn_global_load_lds((gvoid_t*)gB,
          (lvoid_t*)((char*)&Bs[buf][0] + sbase * 16), 16, 0, 0);
    }
  };

  const int NT = K >> 5;
  stage(0, 0);
  __syncthreads();
  for (int t = 0; t < NT; ++t) {
    const int buf = t & 1;
    if (t + 1 < NT) stage(buf ^ 1, (t + 1) << 5);
    short8 af[4], bf[4];
#pragma unroll
    for (int mf = 0; mf < 4; ++mf) af[mf] = *(const short8*)(&As[buf][0] + oaf[mf]);
#pragma unroll
    for (int nf = 0; nf < 4; ++nf)  bf[nf] = *(const short8*)(&Bs[buf][0] + obf[nf]);
#pragma unroll
    for (int mf = 0; mf < 4; ++mf)
#pragma unroll
      for (int nf = 0; nf < 4; ++nf)
        acc[mf][nf] = __builtin_amdgcn_mfma_f32_16x16x32_bf16(af[mf], bf[nf], acc[mf][nf], 0, 0, 0);
    __syncthreads();
  }

  // ---- fused epilogue (R14-proven) ----
  const int ncol = n0 + wc;                 // multiple of 64
  const int seg  = ncol >> 10;              // 0=q 1=k 2=v
  const int h    = (ncol >> 6) & 15;
  const int bb   = m0 >> 11;                // batch (block never crosses 2048)
  const int tb   = (m0 + wr) & 2047;        // wave's first t (mult of 64)
  const size_t base = (size_t)(bb * NHEADS + h) * TT * HDIM;
  float bias_v[4];
#pragma unroll
  for (int nf = 0; nf < 4; ++nf) bias_v[nf] = bias[ncol + nf * 16 + r16];

  if (seg == 2) {
#pragma unroll
    for (int mf = 0; mf < 4; ++mf) {
      int kvt = (tb >> 5) + (mf >> 1);
#pragma unroll
      for (int nf = 0; nf < 4; ++nf) {
        union { unsigned short s4[4]; uint2 u; } w;
#pragma unroll
        for (int rr = 0; rr < 4; ++rr) w.s4[rr] = f2b(acc[mf][nf][rr] + bias_v[nf]);
        size_t addr = base + (size_t)kvt * 2048
                    + (size_t)((nf >> 1) * 2 + (mf & 1)) * 512
                    + (size_t)(g >> 1) * 256
                    + (size_t)((nf & 1) * 16 + r16) * 8 + 4 * (g & 1);
        *(uint2*)(vt + addr) = w.u;
      }
    }
  } else {
#pragma unroll
    for (int mf = 0; mf < 4; ++mf) {
#pragma unroll
      for (int rr = 0; rr < 4; ++rr) {
        int t = tb + mf * 16 + g * 4 + rr;
#pragma unroll
        for (int nf = 0; nf < 2; ++nf) {
          int d = nf * 16 + r16;
          float c = cosb[t * 32 + d], s = sinb[t * 32 + d];
          float v1 = acc[mf][nf][rr]     + bias_v[nf];
          float v2 = acc[mf][nf + 2][rr] + bias_v[nf + 2];
          float o1 = v1 * c - v2 * s;
          float o2 = v1 * s + v2 * c;
          if (seg == 0) {
            qr[base + (size_t)t * HDIM + d]      = f2b(o1 * QSCALE);
            qr[base + (size_t)t * HDIM + d + 32] = f2b(o2 * QSCALE);
          } else {
            size_t ok = base + (size_t)(t >> 5) * 2048 + (size_t)nf * 512
                      + (size_t)(r16 >> 3) * 256 + (size_t)(t & 31) * 8 + (r16 & 7);
            kr[ok]        = f2b(o1);
            kr[ok + 1024] = f2b(o2);   // d+32 -> st+2
          }
        }
      }
    }
  }
}

// ---------------- out-proj GEMM: C[M,N] = A[M,K] @ Bw[N,K]^T + bias (f32 out) ----------------
template<int MF>
__global__ __launch_bounds__(256) void gemm_bt(const unsigned short* __restrict__ A,
                                               const unsigned short* __restrict__ Bw,
                                               const float* __restrict__ bias,
                                               float* __restrict__ Cout,
                                               int M, int N, int K) {
  __shared__ __align__(16) unsigned short As[2][MF * 32 * 32];
  __shared__ __align__(16) unsigned short Bs[2][128 * 32];
  const int tid = threadIdx.x;
  const int lane = tid & 63, wid = tid >> 6;
  const int g = lane >> 4, r16 = lane & 15;
  const int m0 = blockIdx.y * (MF * 32), n0 = blockIdx.x * 128;
  const int wr = (wid >> 1) * (MF * 16), wc = (wid & 1) * 64;
  const int wbase = wid * 64;

  int oaf[MF], obf[4];
#pragma unroll
  for (int mf = 0; mf < MF; ++mf) {
    int row = wr + mf * 16 + r16;
    oaf[mf] = row * 32 + ((g ^ ((row >> 1) & 3)) * 8);
  }
#pragma unroll
  for (int nf = 0; nf < 4; ++nf) {
    int row = wc + nf * 16 + r16;
    obf[nf] = row * 32 + ((g ^ ((row >> 1) & 3)) * 8);
  }

  f32x4 acc[MF][4];
#pragma unroll
  for (int i = 0; i < MF; ++i)
#pragma unroll
    for (int j = 0; j < 4; ++j) acc[i][j] = (f32x4){0.f, 0.f, 0.f, 0.f};

  auto stage = [&](int buf, int k0) {
#pragma unroll
    for (int j = 0; j < MF / 2; ++j) {
      int sbase = j * 256 + wbase;
      int s = sbase + lane;
      int l = s ^ ((s >> 3) & 3);
      const unsigned short* gA = A + (size_t)(m0 + (l >> 2)) * K + k0 + (l & 3) * 8;
      __builtin_amdgcn_global_load_lds((gvoid_t*)gA,
          (lvoid_t*)((char*)&As[buf][0] + sbase * 16), 16, 0, 0);
    }
#pragma unroll
    for (int j = 0; j < 2; ++j) {
      int sbase = j * 256 + wbase;
      int s = sbase + lane;
      int l = s ^ ((s >> 3) & 3);
      const unsigned short* gB = Bw + (size_t)(n0 + (l >> 2)) * K + k0 + (l & 3) * 8;
      __builtin_amdgcn_global_load_lds((gvoid_t*)gB,
          (lvoid_t*)((char*)&Bs[buf][0] + sbase * 16), 16, 0, 0);
    }
  };

  const int NT = K >> 5;
  stage(0, 0);
  __syncthreads();
  for (int t = 0; t < NT; ++t) {
    const int buf = t & 1;
    if (t + 1 < NT) stage(buf ^ 1, (t + 1) << 5);
    short8 af[MF], bf[4];
#pragma unroll
    for (int mf = 0; mf < MF; ++mf) af[mf] = *(const short8*)(&As[buf][0] + oaf[mf]);
#pragma unroll
    for (int nf = 0; nf < 4; ++nf)  bf[nf] = *(const short8*)(&Bs[buf][0] + obf[nf]);
#pragma unroll
    for (int mf = 0; mf < MF; ++mf)
#pragma unroll
      for (int nf = 0; nf < 4; ++nf)
        acc[mf][nf] = __builtin_amdgcn_mfma_f32_16x16x32_bf16(af[mf], bf[nf], acc[mf][nf], 0, 0, 0);
    __syncthreads();
  }
#pragma unroll
  for (int mf = 0; mf < MF; ++mf)
#pragma unroll
    for (int nf = 0; nf < 4; ++nf)
#pragma unroll
      for (int rr = 0; rr < 4; ++rr) {
        int m = m0 + wr + mf * 16 + g * 4 + rr;
        int n = n0 + wc + nf * 16 + r16;
        Cout[(size_t)m * N + n] = acc[mf][nf][rr] + bias[n];
      }
}

// ---------------- flash attention: 8-way split-KV, KVBLK=32, swapped QK^T ----------------
// R20: 512-thread blocks (8 waves); wave w takes steps w, w+8, ... -> serial
// chain per wave halves vs R19 (<=5 steps on the longest tiles). LDS combine
// extends to 8 partials (61KB -> 2 blocks/CU x 8 waves = 4 waves/SIMD, same TLP).
__global__ __launch_bounds__(512, 4) void attn_kernel(const unsigned short* __restrict__ qr,
                                                      const unsigned short* __restrict__ kr,
                                                      const unsigned short* __restrict__ vt,
                                                      const float* __restrict__ gate,
                                                      unsigned short* __restrict__ attn_out) {
  __shared__ float lds_m[8][32];
  __shared__ float lds_l[8][32];
  __shared__ float lds_O[7][64][33];
  const int tid = threadIdx.x;
  const int lane = tid & 63, wid = tid >> 6;   // 8 waves
  const int l31 = lane & 31, hi = lane >> 5;

  // XCD swizzle + longest-first: 2048 blocks
  const int fid = blockIdx.x;
  const int idx = fid >> 3;                 // 0..255
  const int bh = (fid & 7) * 4 + (idx & 3);
  const int qt = 63 - (idx >> 2);
  const int q0 = qt * 32;
  const int b = bh >> 4, h = bh & 15;
  const unsigned short* kptr = kr + (size_t)bh * TT * HDIM;
  const unsigned short* vptr = vt + (size_t)bh * TT * HDIM;
  const int q = q0 + l31;

  short8 qf[4];
#pragma unroll
  for (int st = 0; st < 4; ++st)
    qf[st] = *(const short8*)(qr + (size_t)bh * TT * HDIM + (size_t)q * HDIM + st * 16 + hi * 8);

  f32x16 o0, o1;
#pragma unroll
  for (int r = 0; r < 16; ++r) { o0[r] = 0.f; o1[r] = 0.f; }
  float mrun = -1e30f, lrun = 0.f;

  int kv_lo = q0 - WIN;
  if (kv_lo < 0) kv_lo = 0;
  const int kv_hi = q0 + 32;

  // wave wid handles steps kv_lo + (wid + 8i)*32
  for (int kv = kv_lo + wid * 32; kv < kv_hi; kv += 256) {
    const unsigned short* kf = kptr + (size_t)kv * 64 + lane * 8;
    short8 k0 = *(const short8*)(kf);
    short8 k1 = *(const short8*)(kf + 512);
    short8 k2 = *(const short8*)(kf + 1024);
    short8 k3 = *(const short8*)(kf + 1536);

    f32x16 s;
#pragma unroll
    for (int r = 0; r < 16; ++r) s[r] = 0.f;
    s = __builtin_amdgcn_mfma_f32_32x32x16_bf16(k0, qf[0], s, 0, 0, 0);
    s = __builtin_amdgcn_mfma_f32_32x32x16_bf16(k1, qf[1], s, 0, 0, 0);
    s = __builtin_amdgcn_mfma_f32_32x32x16_bf16(k2, qf[2], s, 0, 0, 0);
    s = __builtin_amdgcn_mfma_f32_32x32x16_bf16(k3, qf[3], s, 0, 0, 0);

    if (kv == q0) {            // causal (global last step)
#pragma unroll
      for (int r = 0; r < 16; ++r) {
        int key = kv + (r & 3) + 8 * (r >> 2) + 4 * hi;
        s[r] = (key <= q) ? s[r] : -1e30f;
      }
    } else if (q0 >= WIN && kv == kv_lo) {   // window edge (global first step)
#pragma unroll
      for (int r = 0; r < 16; ++r) {
        int key = kv + (r & 3) + 8 * (r >> 2) + 4 * hi;
        s[r] = (key + WIN >= q) ? s[r] : -1e30f;
      }
    }

    float t0 = max3f(s[0],  s[1],  s[2]);
    float t1 = max3f(s[3],  s[4],  s[5]);
    float t2 = max3f(s[6],  s[7],  s[8]);
    float t3 = max3f(s[9],  s[10], s[11]);
    float t4 = max3f(s[12], s[13], s[14]);
    float lm = fmaxf(max3f(t0, t1, t2), max3f(t3, t4, s[15]));
    lm = xmax32(lm);

    if (!__all(lm - mrun <= 8.f)) {
      float mnew = fmaxf(mrun, lm);
      float scf = __builtin_exp2f(mrun - mnew);
      mrun = mnew;
      lrun *= scf;
#pragma unroll
      for (int r = 0; r < 16; ++r) { o0[r] *= scf; o1[r] *= scf; }
    }

#pragma unroll
    for (int r = 0; r < 16; ++r) s[r] = __builtin_exp2f(s[r] - mrun);

    float c0 = (s[0] + s[1]) + (s[2] + s[3]);
    float c1 = (s[4] + s[5]) + (s[6] + s[7]);
    float c2 = (s[8] + s[9]) + (s[10] + s[11]);
    float c3 = (s[12] + s[13]) + (s[14] + s[15]);
    lrun += xsum32((c0 + c1) + (c2 + c3));

    unsigned w0 = cvt_pk_bf16(s[0],  s[1]),  w1 = cvt_pk_bf16(s[2],  s[3]);
    unsigned w2 = cvt_pk_bf16(s[4],  s[5]),  w3 = cvt_pk_bf16(s[6],  s[7]);
    unsigned w4 = cvt_pk_bf16(s[8],  s[9]),  w5 = cvt_pk_bf16(s[10], s[11]);
    unsigned w6 = cvt_pk_bf16(s[12], s[13]), w7 = cvt_pk_bf16(s[14], s[15]);
    auto s1p = __builtin_amdgcn_permlane32_swap(w0, w2, false, false);
    auto s2p = __builtin_amdgcn_permlane32_swap(w1, w3, false, false);
    auto s3p = __builtin_amdgcn_permlane32_swap(w4, w6, false, false);
    auto s4p = __builtin_amdgcn_permlane32_swap(w5, w7, false, false);
    union { unsigned u[4]; short8 s8; } pf0, pf1;
    pf0.u[0] = s1p[0]; pf0.u[1] = s2p[0]; pf0.u[2] = s1p[1]; pf0.u[3] = s2p[1];
    pf1.u[0] = s3p[0]; pf1.u[1] = s4p[0]; pf1.u[2] = s3p[1]; pf1.u[3] = s4p[1];

    const unsigned short* vf = vptr + (size_t)kv * 64 + lane * 8;
    short8 vf00 = *(const short8*)(vf);
    short8 vf01 = *(const short8*)(vf + 512);
    short8 vf10 = *(const short8*)(vf + 1024);
    short8 vf11 = *(const short8*)(vf + 1536);

    o0 = __builtin_amdgcn_mfma_f32_32x32x16_bf16(vf00, pf0.s8, o0, 0, 0, 0);
    o1 = __builtin_amdgcn_mfma_f32_32x32x16_bf16(vf10, pf0.s8, o1, 0, 0, 0);
    o0 = __builtin_amdgcn_mfma_f32_32x32x16_bf16(vf01, pf1.s8, o0, 0, 0, 0);
    o1 = __builtin_amdgcn_mfma_f32_32x32x16_bf16(vf11, pf1.s8, o1, 0, 0, 0);
  }

  // ---- combine across the 8 waves ----
  if (hi == 0) { lds_m[wid][l31] = mrun; lds_l[wid][l31] = lrun; }
  __syncthreads();
  float mstar = -1e30f;
#pragma unroll
  for (int w = 0; w < 8; ++w) mstar = fmaxf(mstar, lds_m[w][l31]);
  float myscale = __builtin_exp2f(mrun - mstar);
  if (wid != 0) {
#pragma unroll
    for (int r = 0; r < 16; ++r) {
      lds_O[wid - 1][lane][r]      = o0[r] * myscale;
      lds_O[wid - 1][lane][16 + r] = o1[r] * myscale;
    }
  }
  __syncthreads();
  if (wid == 0) {
    float lstar = 0.f;
#pragma unroll
    for (int w = 0; w < 8; ++w)
      lstar += __builtin_exp2f(lds_m[w][l31] - mstar) * lds_l[w][l31];
    float gv = gate[((size_t)b * TT + q) * NHEADS + h];
    float inv = gv / lstar;
    float of0[16], of1[16];
#pragma unroll
    for (int r = 0; r < 16; ++r) {
      float a0 = o0[r] * myscale, a1 = o1[r] * myscale;
#pragma unroll
      for (int w = 0; w < 7; ++w) {
        a0 += lds_O[w][lane][r];
        a1 += lds_O[w][lane][16 + r];
      }
      of0[r] = a0; of1[r] = a1;
    }
    unsigned short* orow = attn_out + ((size_t)b * TT + q) * DIMM + h * HDIM;
#pragma unroll
    for (int a2 = 0; a2 < 4; ++a2) {
      int d0 = a2 * 8 + hi * 4;
      union { unsigned short s[4]; uint2 u; } x0, x1;
#pragma unroll
      for (int c = 0; c < 4; ++c) {
        x0.s[c] = f2b(of0[a2 * 4 + c] * inv);
        x1.s[c] = f2b(of1[a2 * 4 + c] * inv);
      }
      *(uint2*)(orow + d0) = x0.u;
      *(uint2*)(orow + 32 + d0) = x1.u;
    }
  }
}

// ---------------- workspace layout (bytes) ----------------
#define OFF_XB    ((size_t)0)
#define OFF_WQKV  ((size_t)8388608)
#define OFF_WO    ((size_t)14680064)
#define OFF_BCAT  ((size_t)16777216)
#define OFF_QR    ((size_t)41959424)
#define OFF_KR    ((size_t)50348032)
#define OFF_VT    ((size_t)58736640)
#define OFF_ATTN  ((size_t)67125248)
#define OFF_GATE  ((size_t)75513856)

extern "C" void kernel_launch(void* const* d_in, const int* in_sizes, int n_in,
                              void* d_out, int out_size, void* d_ws, size_t ws_size,
                              hipStream_t stream) {
  const float* x    = (const float*)d_in[0];
  const float* Wq   = (const float*)d_in[1];
  const float* bq   = (const float*)d_in[2];
  const float* Wk   = (const float*)d_in[3];
  const float* bk   = (const float*)d_in[4];
  const float* Wv   = (const float*)d_in[5];
  const float* bv   = (const float*)d_in[6];
  const float* Wo   = (const float*)d_in[7];
  const float* bo   = (const float*)d_in[8];
  const float* Wg   = (const float*)d_in[9];
  const float* bg   = (const float*)d_in[10];
  const float* cosb = (const float*)d_in[11];
  const float* sinb = (const float*)d_in[12];
  float* out = (float*)d_out;
  char* ws = (char*)d_ws;

  unsigned short* xb    = (unsigned short*)(ws + OFF_XB);
  unsigned short* wqkv  = (unsigned short*)(ws + OFF_WQKV);
  unsigned short* wob   = (unsigned short*)(ws + OFF_WO);
  float*          bcat  = (float*)(ws + OFF_BCAT);
  unsigned short* q_r   = (unsigned short*)(ws + OFF_QR);
  unsigned short* k_r   = (unsigned short*)(ws + OFF_KR);
  unsigned short* v_t   = (unsigned short*)(ws + OFF_VT);
  unsigned short* attn  = (unsigned short*)(ws + OFF_ATTN);
  float*          gateb = (float*)(ws + OFF_GATE);

  prep_kernel<<<8195, 256, 0, stream>>>(x, Wq, Wk, Wv, Wo, bq, bk, bv, xb, wqkv, wob, bcat);
  gate_kernel<<<256, 256, 0, stream>>>(x, Wg, bg, gateb);

  // fused QKV projection + RoPE + relayout (128^2 dbuf, plain mapping)
  gemm_qkv<<<dim3(24, 32), 256, 0, stream>>>(xb, wqkv, bcat, cosb, sinb, q_r, k_r, v_t);

  // windowed causal flash attention + gate (8-way split-KV, 512 threads)
  attn_kernel<<<2048, 512, 0, stream>>>(q_r, k_r, v_t, gateb, attn);

  // output projection: [4096,1024] @ [1024,1024]^T + bo (dbuf 2-phase)
  gemm_bt<2><<<dim3(8, 64), 256, 0, stream>>>(attn, wob, bo, out, MTOT, 1024, 1024);
}

// Round 22
// 105.495 us; speedup vs baseline: 1.0969x; 1.0969x over previous
//
#include <hip/hip_runtime.h>

#define DIMM 1024
#define NHEADS 16
#define HDIM 64
#define WIN 1024
#define GATEIN 20
#define BB 2
#define TT 2048
#define MTOT (BB*TT)   // 4096

typedef __attribute__((ext_vector_type(8))) short short8;
typedef __attribute__((ext_vector_type(4))) float f32x4;
typedef __attribute__((ext_vector_type(16))) float f32x16;
typedef const __attribute__((address_space(1))) void gvoid_t;
typedef __attribute__((address_space(3))) void lvoid_t;

__device__ __forceinline__ unsigned short f2b(float f) {
  union { float f; unsigned u; } c; c.f = f;
  unsigned u = c.u + 0x7fffu + ((c.u >> 16) & 1u);
  return (unsigned short)(u >> 16);
}
__device__ __forceinline__ float b2f(unsigned short s) {
  union { unsigned u; float f; } c; c.u = ((unsigned)s) << 16;
  return c.f;
}
__device__ __forceinline__ unsigned cvt_pk_bf16(float lo, float hi) {
  unsigned r;
  asm("v_cvt_pk_bf16_f32 %0, %1, %2" : "=v"(r) : "v"(lo), "v"(hi));
  return r;
}
__device__ __forceinline__ float max3f(float a, float b, float c) {
  return fmaxf(fmaxf(a, b), c);   // clang fuses to v_max3_f32
}
// cross-half (lane ^ 32) reductions via permlane32_swap (VALU, no DS)
__device__ __forceinline__ float xmax32(float x) {
  union { float f; unsigned u; } c; c.f = x;
  auto pr = __builtin_amdgcn_permlane32_swap(c.u, c.u, false, false);
  union { unsigned u; float f; } a, b; a.u = pr[0]; b.u = pr[1];
  return fmaxf(a.f, b.f);
}
__device__ __forceinline__ float xsum32(float x) {
  union { float f; unsigned u; } c; c.f = x;
  auto pr = __builtin_amdgcn_permlane32_swap(c.u, c.u, false, false);
  union { unsigned u; float f; } a, b; a.u = pr[0]; b.u = pr[1];
  return a.f + b.f;
}

#define QSCALE (0.125f * 1.4426950408889634f)

// ---------------- fused prep: bf16-cast x, Wq|Wk|Wv, Wo; biases; GATE ----------------
// blocks 0..8191: conversions; 8192..8194: bias concat; 8195..8450: gate.
__global__ void prep_kernel(const float* __restrict__ x,  const float* __restrict__ Wq,
                            const float* __restrict__ Wk, const float* __restrict__ Wv,
                            const float* __restrict__ Wo, const float* __restrict__ bq,
                            const float* __restrict__ bk, const float* __restrict__ bv,
                            const float* __restrict__ Wg, const float* __restrict__ bg,
                            unsigned short* __restrict__ xb, unsigned short* __restrict__ wqkv,
                            unsigned short* __restrict__ wob, float* __restrict__ bcat,
                            float* __restrict__ gate) {
  int i = blockIdx.x * blockDim.x + threadIdx.x;
  const float* src; unsigned short* dst; int off;
  if (i < 1048576)      { src = x;  dst = xb;             off = i; }
  else if (i < 1310720) { src = Wq; dst = wqkv;           off = i - 1048576; }
  else if (i < 1572864) { src = Wk; dst = wqkv + 1048576; off = i - 1310720; }
  else if (i < 1835008) { src = Wv; dst = wqkv + 2097152; off = i - 1572864; }
  else if (i < 2097152) { src = Wo; dst = wob;            off = i - 1835008; }
  else {
    int j = i - 2097152;
    if (j < 768) {                   // bias f32 copy (blocks 8192..8194)
      const float* bsrc = (j < 256) ? bq : (j < 512) ? bk : bv;
      int bo = (j & 255) * 4;
      int db = (j < 256) ? 0 : (j < 512) ? 1024 : 2048;
      *(float4*)(bcat + db + bo) = *(const float4*)(bsrc + bo);
    } else if (j < 768 + MTOT * NHEADS) {   // gate (blocks 8195..8450)
      int idx = j - 768;             // M*H
      int h = idx & 15;
      int m = idx >> 4;
      const float* xr = x + (size_t)m * DIMM;
      const float* wr = Wg + h * GATEIN;
      float z = bg[h];
#pragma unroll
      for (int g = 0; g < GATEIN; ++g) z += xr[g] * wr[g];
      gate[idx] = 1.f / (1.f + __expf(-z));
    }
    return;
  }
  float4 v = ((const float4*)src)[off];
  union { unsigned short s[4]; uint2 u; } o;
  o.s[0] = f2b(v.x); o.s[1] = f2b(v.y); o.s[2] = f2b(v.z); o.s[3] = f2b(v.w);
  *(uint2*)(dst + (size_t)off * 4) = o.u;
}

// ---------------- QKV GEMM with fused RoPE + relayout epilogue (R14 config) ----------------
// 128x128 tile, 4 waves, swizzled LDS, dbuf 2-phase. N=3072 = [q|k|v].
__global__ __launch_bounds__(256) void gemm_qkv(const unsigned short* __restrict__ A,
                                                const unsigned short* __restrict__ Bw,
                                                const float* __restrict__ bias,
                                                const float* __restrict__ cosb,
                                                const float* __restrict__ sinb,
                                                unsigned short* __restrict__ qr,
                                                unsigned short* __restrict__ kr,
                                                unsigned short* __restrict__ vt) {
  const int K = DIMM;
  __shared__ __align__(16) unsigned short As[2][128 * 32];
  __shared__ __align__(16) unsigned short Bs[2][128 * 32];
  const int tid = threadIdx.x;
  const int lane = tid & 63, wid = tid >> 6;
  const int g = lane >> 4, r16 = lane & 15;
  const int m0 = blockIdx.y * 128, n0 = blockIdx.x * 128;
  const int wr = (wid >> 1) * 64, wc = (wid & 1) * 64;
  const int wbase = wid * 64;

  int oaf[4], obf[4];
#pragma unroll
  for (int mf = 0; mf < 4; ++mf) {
    int row = wr + mf * 16 + r16;
    oaf[mf] = row * 32 + ((g ^ ((row >> 1) & 3)) * 8);
  }
#pragma unroll
  for (int nf = 0; nf < 4; ++nf) {
    int row = wc + nf * 16 + r16;
    obf[nf] = row * 32 + ((g ^ ((row >> 1) & 3)) * 8);
  }

  f32x4 acc[4][4];
#pragma unroll
  for (int i = 0; i < 4; ++i)
#pragma unroll
    for (int j2 = 0; j2 < 4; ++j2) acc[i][j2] = (f32x4){0.f, 0.f, 0.f, 0.f};

  auto stage = [&](int buf, int k0) {
#pragma unroll
    for (int jj = 0; jj < 2; ++jj) {
      int sbase = jj * 256 + wbase;
      int s = sbase + lane;
      int l = s ^ ((s >> 3) & 3);
      const unsigned short* gA = A + (size_t)(m0 + (l >> 2)) * K + k0 + (l & 3) * 8;
      __builtin_amdgcn_global_load_lds((gvoid_t*)gA,
          (lvoid_t*)((char*)&As[buf][0] + sbase * 16), 16, 0, 0);
      const unsigned short* gB = Bw + (size_t)(n0 + (l >> 2)) * K + k0 + (l & 3) * 8;
      __builtin_amdgcn_global_load_lds((gvoid_t*)gB,
          (lvoid_t*)((char*)&Bs[buf][0] + sbase * 16), 16, 0, 0);
    }
  };

  const int NT = K >> 5;
  stage(0, 0);
  __syncthreads();
  for (int t = 0; t < NT; ++t) {
    const int buf = t & 1;
    if (t + 1 < NT) stage(buf ^ 1, (t + 1) << 5);
    short8 af[4], bf[4];
#pragma unroll
    for (int mf = 0; mf < 4; ++mf) af[mf] = *(const short8*)(&As[buf][0] + oaf[mf]);
#pragma unroll
    for (int nf = 0; nf < 4; ++nf)  bf[nf] = *(const short8*)(&Bs[buf][0] + obf[nf]);
#pragma unroll
    for (int mf = 0; mf < 4; ++mf)
#pragma unroll
      for (int nf = 0; nf < 4; ++nf)
        acc[mf][nf] = __builtin_amdgcn_mfma_f32_16x16x32_bf16(af[mf], bf[nf], acc[mf][nf], 0, 0, 0);
    __syncthreads();
  }

  // ---- fused epilogue (R14-proven) ----
  const int ncol = n0 + wc;                 // multiple of 64
  const int seg  = ncol >> 10;              // 0=q 1=k 2=v
  const int h    = (ncol >> 6) & 15;
  const int bb   = m0 >> 11;                // batch (block never crosses 2048)
  const int tb   = (m0 + wr) & 2047;        // wave's first t (mult of 64)
  const size_t base = (size_t)(bb * NHEADS + h) * TT * HDIM;
  float bias_v[4];
#pragma unroll
  for (int nf = 0; nf < 4; ++nf) bias_v[nf] = bias[ncol + nf * 16 + r16];

  if (seg == 2) {
#pragma unroll
    for (int mf = 0; mf < 4; ++mf) {
      int kvt = (tb >> 5) + (mf >> 1);
#pragma unroll
      for (int nf = 0; nf < 4; ++nf) {
        union { unsigned short s4[4]; uint2 u; } w;
#pragma unroll
        for (int rr = 0; rr < 4; ++rr) w.s4[rr] = f2b(acc[mf][nf][rr] + bias_v[nf]);
        size_t addr = base + (size_t)kvt * 2048
                    + (size_t)((nf >> 1) * 2 + (mf & 1)) * 512
                    + (size_t)(g >> 1) * 256
                    + (size_t)((nf & 1) * 16 + r16) * 8 + 4 * (g & 1);
        *(uint2*)(vt + addr) = w.u;
      }
    }
  } else {
#pragma unroll
    for (int mf = 0; mf < 4; ++mf) {
#pragma unroll
      for (int rr = 0; rr < 4; ++rr) {
        int t = tb + mf * 16 + g * 4 + rr;
#pragma unroll
        for (int nf = 0; nf < 2; ++nf) {
          int d = nf * 16 + r16;
          float c = cosb[t * 32 + d], s = sinb[t * 32 + d];
          float v1 = acc[mf][nf][rr]     + bias_v[nf];
          float v2 = acc[mf][nf + 2][rr] + bias_v[nf + 2];
          float o1 = v1 * c - v2 * s;
          float o2 = v1 * s + v2 * c;
          if (seg == 0) {
            qr[base + (size_t)t * HDIM + d]      = f2b(o1 * QSCALE);
            qr[base + (size_t)t * HDIM + d + 32] = f2b(o2 * QSCALE);
          } else {
            size_t ok = base + (size_t)(t >> 5) * 2048 + (size_t)nf * 512
                      + (size_t)(r16 >> 3) * 256 + (size_t)(t & 31) * 8 + (r16 & 7);
            kr[ok]        = f2b(o1);
            kr[ok + 1024] = f2b(o2);   // d+32 -> st+2
          }
        }
      }
    }
  }
}

// ---------------- out-proj GEMM: C[M,N] = A[M,K] @ Bw[N,K]^T + bias (f32 out) ----------------
template<int MF>
__global__ __launch_bounds__(256) void gemm_bt(const unsigned short* __restrict__ A,
                                               const unsigned short* __restrict__ Bw,
                                               const float* __restrict__ bias,
                                               float* __restrict__ Cout,
                                               int M, int N, int K) {
  __shared__ __align__(16) unsigned short As[2][MF * 32 * 32];
  __shared__ __align__(16) unsigned short Bs[2][128 * 32];
  const int tid = threadIdx.x;
  const int lane = tid & 63, wid = tid >> 6;
  const int g = lane >> 4, r16 = lane & 15;
  const int m0 = blockIdx.y * (MF * 32), n0 = blockIdx.x * 128;
  const int wr = (wid >> 1) * (MF * 16), wc = (wid & 1) * 64;
  const int wbase = wid * 64;

  int oaf[MF], obf[4];
#pragma unroll
  for (int mf = 0; mf < MF; ++mf) {
    int row = wr + mf * 16 + r16;
    oaf[mf] = row * 32 + ((g ^ ((row >> 1) & 3)) * 8);
  }
#pragma unroll
  for (int nf = 0; nf < 4; ++nf) {
    int row = wc + nf * 16 + r16;
    obf[nf] = row * 32 + ((g ^ ((row >> 1) & 3)) * 8);
  }

  f32x4 acc[MF][4];
#pragma unroll
  for (int i = 0; i < MF; ++i)
#pragma unroll
    for (int j = 0; j < 4; ++j) acc[i][j] = (f32x4){0.f, 0.f, 0.f, 0.f};

  auto stage = [&](int buf, int k0) {
#pragma unroll
    for (int j = 0; j < MF / 2; ++j) {
      int sbase = j * 256 + wbase;
      int s = sbase + lane;
      int l = s ^ ((s >> 3) & 3);
      const unsigned short* gA = A + (size_t)(m0 + (l >> 2)) * K + k0 + (l & 3) * 8;
      __builtin_amdgcn_global_load_lds((gvoid_t*)gA,
          (lvoid_t*)((char*)&As[buf][0] + sbase * 16), 16, 0, 0);
    }
#pragma unroll
    for (int j = 0; j < 2; ++j) {
      int sbase = j * 256 + wbase;
      int s = sbase + lane;
      int l = s ^ ((s >> 3) & 3);
      const unsigned short* gB = Bw + (size_t)(n0 + (l >> 2)) * K + k0 + (l & 3) * 8;
      __builtin_amdgcn_global_load_lds((gvoid_t*)gB,
          (lvoid_t*)((char*)&Bs[buf][0] + sbase * 16), 16, 0, 0);
    }
  };

  const int NT = K >> 5;
  stage(0, 0);
  __syncthreads();
  for (int t = 0; t < NT; ++t) {
    const int buf = t & 1;
    if (t + 1 < NT) stage(buf ^ 1, (t + 1) << 5);
    short8 af[MF], bf[4];
#pragma unroll
    for (int mf = 0; mf < MF; ++mf) af[mf] = *(const short8*)(&As[buf][0] + oaf[mf]);
#pragma unroll
    for (int nf = 0; nf < 4; ++nf)  bf[nf] = *(const short8*)(&Bs[buf][0] + obf[nf]);
#pragma unroll
    for (int mf = 0; mf < MF; ++mf)
#pragma unroll
      for (int nf = 0; nf < 4; ++nf)
        acc[mf][nf] = __builtin_amdgcn_mfma_f32_16x16x32_bf16(af[mf], bf[nf], acc[mf][nf], 0, 0, 0);
    __syncthreads();
  }
#pragma unroll
  for (int mf = 0; mf < MF; ++mf)
#pragma unroll
    for (int nf = 0; nf < 4; ++nf)
#pragma unroll
      for (int rr = 0; rr < 4; ++rr) {
        int m = m0 + wr + mf * 16 + g * 4 + rr;
        int n = n0 + wc + nf * 16 + r16;
        Cout[(size_t)m * N + n] = acc[mf][nf][rr] + bias[n];
      }
}

// ---------------- flash attention: 4-way split-KV, KVBLK=32, swapped QK^T ----------------
// Register-dieted for 4 waves/SIMD (<=128 unified regs, m69 bracket).
__global__ __launch_bounds__(256, 4) void attn_kernel(const unsigned short* __restrict__ qr,
                                                      const unsigned short* __restrict__ kr,
                                                      const unsigned short* __restrict__ vt,
                                                      const float* __restrict__ gate,
                                                      unsigned short* __restrict__ attn_out) {
  __shared__ float lds_m[4][32];
  __shared__ float lds_l[4][32];
  __shared__ float lds_O[3][64][33];
  const int tid = threadIdx.x;
  const int lane = tid & 63, wid = tid >> 6;
  const int l31 = lane & 31, hi = lane >> 5;

  const int fid = blockIdx.x;
  const int idx = fid >> 3;                 // 0..255
  const int bh = (fid & 7) * 4 + (idx & 3);
  const int qt = 63 - (idx >> 2);
  const int q0 = qt * 32;
  const int b = bh >> 4, h = bh & 15;
  const unsigned short* kptr = kr + (size_t)bh * TT * HDIM;
  const unsigned short* vptr = vt + (size_t)bh * TT * HDIM;
  const int q = q0 + l31;

  short8 qf[4];
#pragma unroll
  for (int st = 0; st < 4; ++st)
    qf[st] = *(const short8*)(qr + (size_t)bh * TT * HDIM + (size_t)q * HDIM + st * 16 + hi * 8);

  f32x16 o0, o1;
#pragma unroll
  for (int r = 0; r < 16; ++r) { o0[r] = 0.f; o1[r] = 0.f; }
  float mrun = -1e30f, lrun = 0.f;

  int kv_lo = q0 - WIN;
  if (kv_lo < 0) kv_lo = 0;
  const int kv_hi = q0 + 32;

  for (int kv = kv_lo + wid * 32; kv < kv_hi; kv += 128) {
    const unsigned short* kf = kptr + (size_t)kv * 64 + lane * 8;
    short8 k0 = *(const short8*)(kf);
    short8 k1 = *(const short8*)(kf + 512);
    short8 k2 = *(const short8*)(kf + 1024);
    short8 k3 = *(const short8*)(kf + 1536);

    f32x16 s;
#pragma unroll
    for (int r = 0; r < 16; ++r) s[r] = 0.f;
    s = __builtin_amdgcn_mfma_f32_32x32x16_bf16(k0, qf[0], s, 0, 0, 0);
    s = __builtin_amdgcn_mfma_f32_32x32x16_bf16(k1, qf[1], s, 0, 0, 0);
    s = __builtin_amdgcn_mfma_f32_32x32x16_bf16(k2, qf[2], s, 0, 0, 0);
    s = __builtin_amdgcn_mfma_f32_32x32x16_bf16(k3, qf[3], s, 0, 0, 0);

    if (kv == q0) {
#pragma unroll
      for (int r = 0; r < 16; ++r) {
        int key = kv + (r & 3) + 8 * (r >> 2) + 4 * hi;
        s[r] = (key <= q) ? s[r] : -1e30f;
      }
    } else if (q0 >= WIN && kv == kv_lo) {
#pragma unroll
      for (int r = 0; r < 16; ++r) {
        int key = kv + (r & 3) + 8 * (r >> 2) + 4 * hi;
        s[r] = (key + WIN >= q) ? s[r] : -1e30f;
      }
    }

    float t0 = max3f(s[0],  s[1],  s[2]);
    float t1 = max3f(s[3],  s[4],  s[5]);
    float t2 = max3f(s[6],  s[7],  s[8]);
    float t3 = max3f(s[9],  s[10], s[11]);
    float t4 = max3f(s[12], s[13], s[14]);
    float lm = fmaxf(max3f(t0, t1, t2), max3f(t3, t4, s[15]));
    lm = xmax32(lm);

    if (!__all(lm - mrun <= 8.f)) {
      float mnew = fmaxf(mrun, lm);
      float scf = __builtin_exp2f(mrun - mnew);
      mrun = mnew;
      lrun *= scf;
#pragma unroll
      for (int r = 0; r < 16; ++r) { o0[r] *= scf; o1[r] *= scf; }
    }

#pragma unroll
    for (int r = 0; r < 16; ++r) s[r] = __builtin_exp2f(s[r] - mrun);

    float c0 = (s[0] + s[1]) + (s[2] + s[3]);
    float c1 = (s[4] + s[5]) + (s[6] + s[7]);
    float c2 = (s[8] + s[9]) + (s[10] + s[11]);
    float c3 = (s[12] + s[13]) + (s[14] + s[15]);
    lrun += xsum32((c0 + c1) + (c2 + c3));

    unsigned w0 = cvt_pk_bf16(s[0],  s[1]),  w1 = cvt_pk_bf16(s[2],  s[3]);
    unsigned w2 = cvt_pk_bf16(s[4],  s[5]),  w3 = cvt_pk_bf16(s[6],  s[7]);
    unsigned w4 = cvt_pk_bf16(s[8],  s[9]),  w5 = cvt_pk_bf16(s[10], s[11]);
    unsigned w6 = cvt_pk_bf16(s[12], s[13]), w7 = cvt_pk_bf16(s[14], s[15]);
    auto s1p = __builtin_amdgcn_permlane32_swap(w0, w2, false, false);
    auto s2p = __builtin_amdgcn_permlane32_swap(w1, w3, false, false);
    auto s3p = __builtin_amdgcn_permlane32_swap(w4, w6, false, false);
    auto s4p = __builtin_amdgcn_permlane32_swap(w5, w7, false, false);
    union { unsigned u[4]; short8 s8; } pf0, pf1;
    pf0.u[0] = s1p[0]; pf0.u[1] = s2p[0]; pf0.u[2] = s1p[1]; pf0.u[3] = s2p[1];
    pf1.u[0] = s3p[0]; pf1.u[1] = s4p[0]; pf1.u[2] = s3p[1]; pf1.u[3] = s4p[1];

    const unsigned short* vf = vptr + (size_t)kv * 64 + lane * 8;
    short8 vf00 = *(const short8*)(vf);
    short8 vf01 = *(const short8*)(vf + 512);
    short8 vf10 = *(const short8*)(vf + 1024);
    short8 vf11 = *(const short8*)(vf + 1536);

    o0 = __builtin_amdgcn_mfma_f32_32x32x16_bf16(vf00, pf0.s8, o0, 0, 0, 0);
    o1 = __builtin_amdgcn_mfma_f32_32x32x16_bf16(vf10, pf0.s8, o1, 0, 0, 0);
    o0 = __builtin_amdgcn_mfma_f32_32x32x16_bf16(vf01, pf1.s8, o0, 0, 0, 0);
    o1 = __builtin_amdgcn_mfma_f32_32x32x16_bf16(vf11, pf1.s8, o1, 0, 0, 0);
  }

  // ---- combine across the 4 waves ----
  if (hi == 0) { lds_m[wid][l31] = mrun; lds_l[wid][l31] = lrun; }
  __syncthreads();
  float m0 = lds_m[0][l31], m1 = lds_m[1][l31], m2 = lds_m[2][l31], m3 = lds_m[3][l31];
  float mstar = fmaxf(fmaxf(m0, m1), fmaxf(m2, m3));
  float myscale = __builtin_exp2f(mrun - mstar);
  if (wid != 0) {
#pragma unroll
    for (int r = 0; r < 16; ++r) {
      lds_O[wid - 1][lane][r]      = o0[r] * myscale;
      lds_O[wid - 1][lane][16 + r] = o1[r] * myscale;
    }
  }
  __syncthreads();
  if (wid == 0) {
    float lstar = __builtin_exp2f(m0 - mstar) * lds_l[0][l31]
                + __builtin_exp2f(m1 - mstar) * lds_l[1][l31]
                + __builtin_exp2f(m2 - mstar) * lds_l[2][l31]
                + __builtin_exp2f(m3 - mstar) * lds_l[3][l31];
    float gv = gate[((size_t)b * TT + q) * NHEADS + h];
    float inv = gv / lstar;
    float of0[16], of1[16];
#pragma unroll
    for (int r = 0; r < 16; ++r) {
      of0[r] = o0[r] * myscale + lds_O[0][lane][r]      + lds_O[1][lane][r]      + lds_O[2][lane][r];
      of1[r] = o1[r] * myscale + lds_O[0][lane][16 + r] + lds_O[1][lane][16 + r] + lds_O[2][lane][16 + r];
    }
    unsigned short* orow = attn_out + ((size_t)b * TT + q) * DIMM + h * HDIM;
#pragma unroll
    for (int a2 = 0; a2 < 4; ++a2) {
      int d0 = a2 * 8 + hi * 4;
      union { unsigned short s[4]; uint2 u; } x0, x1;
#pragma unroll
      for (int c = 0; c < 4; ++c) {
        x0.s[c] = f2b(of0[a2 * 4 + c] * inv);
        x1.s[c] = f2b(of1[a2 * 4 + c] * inv);
      }
      *(uint2*)(orow + d0) = x0.u;
      *(uint2*)(orow + 32 + d0) = x1.u;
    }
  }
}

// ---------------- workspace layout (bytes) ----------------
#define OFF_XB    ((size_t)0)
#define OFF_WQKV  ((size_t)8388608)
#define OFF_WO    ((size_t)14680064)
#define OFF_BCAT  ((size_t)16777216)
#define OFF_QR    ((size_t)41959424)
#define OFF_KR    ((size_t)50348032)
#define OFF_VT    ((size_t)58736640)
#define OFF_ATTN  ((size_t)67125248)
#define OFF_GATE  ((size_t)75513856)

extern "C" void kernel_launch(void* const* d_in, const int* in_sizes, int n_in,
                              void* d_out, int out_size, void* d_ws, size_t ws_size,
                              hipStream_t stream) {
  const float* x    = (const float*)d_in[0];
  const float* Wq   = (const float*)d_in[1];
  const float* bq   = (const float*)d_in[2];
  const float* Wk   = (const float*)d_in[3];
  const float* bk   = (const float*)d_in[4];
  const float* Wv   = (const float*)d_in[5];
  const float* bv   = (const float*)d_in[6];
  const float* Wo   = (const float*)d_in[7];
  const float* bo   = (const float*)d_in[8];
  const float* Wg   = (const float*)d_in[9];
  const float* bg   = (const float*)d_in[10];
  const float* cosb = (const float*)d_in[11];
  const float* sinb = (const float*)d_in[12];
  float* out = (float*)d_out;
  char* ws = (char*)d_ws;

  unsigned short* xb    = (unsigned short*)(ws + OFF_XB);
  unsigned short* wqkv  = (unsigned short*)(ws + OFF_WQKV);
  unsigned short* wob   = (unsigned short*)(ws + OFF_WO);
  float*          bcat  = (float*)(ws + OFF_BCAT);
  unsigned short* q_r   = (unsigned short*)(ws + OFF_QR);
  unsigned short* k_r   = (unsigned short*)(ws + OFF_KR);
  unsigned short* v_t   = (unsigned short*)(ws + OFF_VT);
  unsigned short* attn  = (unsigned short*)(ws + OFF_ATTN);
  float*          gateb = (float*)(ws + OFF_GATE);

  // conversions + biases + gate in one launch (blocks: 8192 cvt, 3 bias, 256 gate)
  prep_kernel<<<8451, 256, 0, stream>>>(x, Wq, Wk, Wv, Wo, bq, bk, bv, Wg, bg,
                                        xb, wqkv, wob, bcat, gateb);

  // fused QKV projection + RoPE + relayout (128^2 dbuf, plain mapping)
  gemm_qkv<<<dim3(24, 32), 256, 0, stream>>>(xb, wqkv, bcat, cosb, sinb, q_r, k_r, v_t);

  // windowed causal flash attention + gate (4-way split-KV, 4 waves/SIMD)
  attn_kernel<<<2048, 256, 0, stream>>>(q_r, k_r, v_t, gateb, attn);

  // output projection: [4096,1024] @ [1024,1024]^T + bo (dbuf 2-phase)
  gemm_bt<2><<<dim3(8, 64), 256, 0, stream>>>(attn, wob, bo, out, MTOT, 1024, 1024);
}